// Round 12
// baseline (1529.526 us; speedup 1.0000x reference)
//
#include <hip/hip_runtime.h>

#define NPTS    6144
#define RESCALE (1.0f / 1024.0f)  // per-iteration overflow guard (cancels at final normalize)

typedef float v2f __attribute__((ext_vector_type(2)));

// ---- agent(device)-scope atomic helpers (coherent across XCDs) ----
#define AL_I(p)       __hip_atomic_load((p),  __ATOMIC_RELAXED, __HIP_MEMORY_SCOPE_AGENT)
#define AL_ACQ_I(p)   __hip_atomic_load((p),  __ATOMIC_ACQUIRE, __HIP_MEMORY_SCOPE_AGENT)
#define AL_F(p)       __hip_atomic_load((p),  __ATOMIC_RELAXED, __HIP_MEMORY_SCOPE_AGENT)
#define AS_F(p, v)    __hip_atomic_store((p), (v), __ATOMIC_RELAXED, __HIP_MEMORY_SCOPE_AGENT)
#define AS_REL_I(p,v) __hip_atomic_store((p), (v), __ATOMIC_RELEASE, __HIP_MEMORY_SCOPE_AGENT)

// ---------------- fused kernel geometry ----------------
// 1024 blocks x 256 thr (R9/R11-proven co-resident). Block b OWNS i-range
// [6b, 6b+6): full dot over all j -> block-internal reduction -> plain store.
// NO atomics, NO dst zeroing, perfect load balance across blocks.
#define IBLK   256
#define GRIDSZ 1024
#define IPB    (NPTS / GRIDSZ)    // 6 i's owned per block
#define JG     12                 // j-groups per thread (2 j's each)
#define JSTRIDE (2 * IBLK)        // 512 j's per group across the block

// Lightweight grid barrier: epoch-valued flags (poison 0xAAAAAAAA != 1..11,
// so no init needed; epochs increase within a launch -> replay-safe).
__device__ __forceinline__ void gbar(int* __restrict__ arrive, int* __restrict__ go,
                                     int epoch, int b, int tid) {
  asm volatile("s_waitcnt vmcnt(0)" ::: "memory");   // drain this wave's stores
  __syncthreads();                                   // whole block drained
  if (b == 0) {
    if (tid == 0) AS_REL_I(&arrive[0], epoch);
    for (;;) {
      int bad = 0;
      for (int f = tid; f < GRIDSZ; f += IBLK) bad |= (AL_I(&arrive[f]) != epoch);
      if (__syncthreads_or(bad) == 0) break;
      __builtin_amdgcn_s_sleep(2);
    }
    if (tid == 0) AS_REL_I(go, epoch);
  } else {
    if (tid == 0) {
      AS_REL_I(&arrive[b], epoch);
      while (AL_ACQ_I(go) != epoch) __builtin_amdgcn_s_sleep(2);
    }
    __syncthreads();
  }
}

template <bool ONES>
__device__ __forceinline__ void matvec_phase(
    const float4* __restrict__ rec, const float* __restrict__ z3a,
    const float* __restrict__ vsrc, float* __restrict__ vdst,
    int b, int tid,
    const v2f* X2, const v2f* Y2, const v2f* X3, const v2f* Y3, const v2f* Z3,
    float lred[4][IPB])
{
  v2f acc[IPB];
#pragma unroll
  for (int u = 0; u < IPB; ++u) acc[u] = (v2f){0.0f, 0.0f};

  const v2f kM100 = (v2f){-100.0f, -100.0f};
  const v2f k200  = (v2f){ 200.0f,  200.0f};
  const v2f kOne  = (v2f){   1.0f,    1.0f};
  const v2f kZero = (v2f){   0.0f,    0.0f};

#pragma unroll 2
  for (int g = 0; g < JG; ++g) {
    const int j = g * JSTRIDE + 2 * tid;          // coalesced: lane-adjacent j-pairs
    const float4 r0 = rec[j];                     // normal loads: L2-warm all phases
    const float4 r1 = rec[j + 1];
    const float2 zz = *(const float2*)&z3a[j];
    v2f vj;
    if (ONES) vj = (v2f){1.0f, 1.0f};
    else      vj = (v2f){AL_F(&vsrc[j]), AL_F(&vsrc[j + 1])};  // LLC-coherent
    const v2f jx2 = (v2f){r0.x, r1.x}, jy2 = (v2f){r0.y, r1.y};
    const v2f jx3 = (v2f){r0.z, r1.z}, jy3 = (v2f){r0.w, r1.w};
    const v2f jz3 = (v2f){zz.x, zz.y};
#pragma unroll
    for (int u = 0; u < IPB; ++u) {
      v2f dx = jx2 - X2[u], dy = jy2 - Y2[u];
      v2f a  = __builtin_elementwise_fma(dy, dy, dx * dx);              // ||dp2||^2
      v2f ex = jx3 - X3[u], ey = jy3 - Y3[u], ez = jz3 - Z3[u];
      v2f bb = __builtin_elementwise_fma(
                   ez, ez, __builtin_elementwise_fma(ey, ey, ex * ex)); // ||dp3||^2
      v2f ab = a * bb;
      v2f s  = (v2f){__builtin_amdgcn_sqrtf(ab.x),
                     __builtin_amdgcn_sqrtf(ab.y)};                     // bare v_sqrt_f32
      // (d2-d3)^2 = a+b-2*sqrt(ab);  S = max(0, 1 - 100*(a+b) + 200*sqrt(ab))
      v2f w  = __builtin_elementwise_fma(a + bb, kM100, kOne);
      w = __builtin_elementwise_fma(s, k200, w);
      w = __builtin_elementwise_max(w, kZero);
      acc[u] = __builtin_elementwise_fma(w, vj, acc[u]);
    }
  }

  // block-internal reduction: wave shuffle, then 4-wave LDS combine
  float r[IPB];
#pragma unroll
  for (int u = 0; u < IPB; ++u) {
    r[u] = acc[u].x + acc[u].y;
#pragma unroll
    for (int off = 32; off > 0; off >>= 1) r[u] += __shfl_down(r[u], off, 64);
  }
  if ((tid & 63) == 0) {
#pragma unroll
    for (int u = 0; u < IPB; ++u) lred[tid >> 6][u] = r[u];
  }
  __syncthreads();
  if (tid < IPB) {
    float s4 = lred[0][tid] + lred[1][tid] + lred[2][tid] + lred[3][tid];
    AS_F(&vdst[b * IPB + tid], s4 * RESCALE);     // exclusive owner: plain agent store
  }
}

// One kernel: prep -> 10 power iterations (custom barriers) -> finalize.
__global__ __launch_bounds__(IBLK, 4) void power_kernel(
    const float* __restrict__ p2, const float* __restrict__ p3,
    float4* __restrict__ rec, float* __restrict__ z3a,
    float* __restrict__ vA, float* __restrict__ vB,
    int* __restrict__ arrive, int* __restrict__ go,
    float* __restrict__ out)
{
  const int tid = threadIdx.x;
  const int b   = blockIdx.x;
  __shared__ float lred[4][IPB];

  // ---- prep: each block publishes its own 6 points (agent stores) ----
  if (tid < IPB) {
    int i = b * IPB + tid;
    float* r = (float*)&rec[i];
    AS_F(&r[0], p2[2 * i]);  AS_F(&r[1], p2[2 * i + 1]);
    AS_F(&r[2], p3[3 * i]);  AS_F(&r[3], p3[3 * i + 1]);
    AS_F(&z3a[i], p3[3 * i + 2]);
  }

  // ---- i-side splats straight from inputs (own points, no cross-block dep) ----
  v2f X2[IPB], Y2[IPB], X3[IPB], Y3[IPB], Z3[IPB];
#pragma unroll
  for (int u = 0; u < IPB; ++u) {
    int i = b * IPB + u;
    float x2 = p2[2 * i], y2 = p2[2 * i + 1];
    float x3 = p3[3 * i], y3 = p3[3 * i + 1], z3 = p3[3 * i + 2];
    X2[u] = (v2f){x2, x2}; Y2[u] = (v2f){y2, y2};
    X3[u] = (v2f){x3, x3}; Y3[u] = (v2f){y3, y3}; Z3[u] = (v2f){z3, z3};
  }

  gbar(arrive, go, 1, b, tid);    // rec/z3a published

  // ---- phase 0: v = ones -> vA ----
  matvec_phase<true>(rec, z3a, vB, vA, b, tid, X2, Y2, X3, Y3, Z3, lred);

  // ---- phases 1..9: ping-pong vA <-> vB ----
#pragma unroll 1
  for (int k = 1; k < 10; ++k) {
    gbar(arrive, go, k + 1, b, tid);
    const float* vs = (k & 1) ? vA : vB;
    float*       vd = (k & 1) ? vB : vA;
    matvec_phase<false>(rec, z3a, vs, vd, b, tid, X2, Y2, X3, Y3, Z3, lred);
  }
  gbar(arrive, go, 11, b, tid);   // final v (in vB) published

  // ---- finalize: every block computes the norm, stores its own 6 outputs ----
  float ss = 0.0f;
  for (int k = tid; k < NPTS; k += IBLK) {
    float x = AL_F(&vB[k]);
    ss = fmaf(x, x, ss);
  }
  for (int off = 32; off > 0; off >>= 1) ss += __shfl_down(ss, off, 64);
  __shared__ float wsum[4];
  if ((tid & 63) == 0) wsum[tid >> 6] = ss;
  __syncthreads();
  float inv = 1.0f / (sqrtf(wsum[0] + wsum[1] + wsum[2] + wsum[3]) + 1e-6f);
  if (tid < IPB) {
    int i = b * IPB + tid;
    out[i] = AL_F(&vB[i]) * inv;
  }
}

// ---------------- fallback: proven R7 multi-launch path (~200 us) ----------------
#define FB_IPT    4
#define FB_NCH    2
#define FB_IBLK   128
#define FB_ISPAN  (FB_IBLK * FB_IPT)   // 512
#define FB_NIBLK  (NPTS / FB_ISPAN)    // 12
#define FB_JPART  384
#define FB_JLEN   (NPTS / FB_JPART)    // 16

__global__ __launch_bounds__(FB_IBLK) void fb_prep_kernel(
    const float* __restrict__ p2, const float* __restrict__ p3,
    float4* __restrict__ rec, float* __restrict__ z3a,
    float* __restrict__ vA, float* __restrict__ vB) {
  int i = blockIdx.x * FB_IBLK + threadIdx.x;
  if (i >= NPTS) return;
  rec[i] = make_float4(p2[2 * i], p2[2 * i + 1], p3[3 * i], p3[3 * i + 1]);
  z3a[i] = p3[3 * i + 2];
  vA[i] = 1.0f;
  vB[i] = 0.0f;
}

__global__ __launch_bounds__(FB_IBLK) void fb_matvec_kernel(
    const float4* __restrict__ rec, const float* __restrict__ z3a,
    const float* __restrict__ vsrc, float* __restrict__ vdst,
    float* __restrict__ vzero) {
  const int ib = blockIdx.x % FB_NIBLK;
  const int jp = blockIdx.x / FB_NIBLK;
  const int i0 = ib * FB_ISPAN + threadIdx.x;

  const int j0 = jp * FB_JLEN;
  float4 RJ[FB_JLEN];
  float  ZJ[FB_JLEN], VJ[FB_JLEN];
#pragma unroll
  for (int jj = 0; jj < FB_JLEN; ++jj) {
    RJ[jj] = rec[j0 + jj]; ZJ[jj] = z3a[j0 + jj]; VJ[jj] = vsrc[j0 + jj];
  }

  v2f X2[FB_NCH], Y2[FB_NCH], X3[FB_NCH], Y3[FB_NCH], Z3[FB_NCH], acc[FB_NCH];
#pragma unroll
  for (int c = 0; c < FB_NCH; ++c) {
    const int ia  = i0 + (2 * c + 0) * FB_IBLK;
    const int ib2 = i0 + (2 * c + 1) * FB_IBLK;
    float4 ra = rec[ia], rb = rec[ib2];
    X2[c] = (v2f){ra.x, rb.x}; Y2[c] = (v2f){ra.y, rb.y};
    X3[c] = (v2f){ra.z, rb.z}; Y3[c] = (v2f){ra.w, rb.w};
    Z3[c] = (v2f){z3a[ia], z3a[ib2]};
    acc[c] = (v2f){0.0f, 0.0f};
    if (jp == 0) { vzero[ia] = 0.0f; vzero[ib2] = 0.0f; }
  }

  const v2f kM100 = (v2f){-100.0f, -100.0f};
  const v2f k200  = (v2f){ 200.0f,  200.0f};
  const v2f kOne  = (v2f){   1.0f,    1.0f};
  const v2f kZero = (v2f){   0.0f,    0.0f};

#pragma unroll
  for (int jj = 0; jj < FB_JLEN; ++jj) {
    const float4 rj = RJ[jj];
    const float  zj = ZJ[jj];
    const float  vj = VJ[jj];
#pragma unroll
    for (int c = 0; c < FB_NCH; ++c) {
      v2f dx = X2[c] - rj.x, dy = Y2[c] - rj.y;
      v2f a  = __builtin_elementwise_fma(dy, dy, dx * dx);
      v2f ex = X3[c] - rj.z, ey = Y3[c] - rj.w, ez = Z3[c] - zj;
      v2f b  = __builtin_elementwise_fma(
                   ez, ez, __builtin_elementwise_fma(ey, ey, ex * ex));
      v2f ab = a * b;
      v2f s  = (v2f){__builtin_amdgcn_sqrtf(ab.x), __builtin_amdgcn_sqrtf(ab.y)};
      v2f w  = __builtin_elementwise_fma(a + b, kM100, kOne);
      w = __builtin_elementwise_fma(s, k200, w);
      w = __builtin_elementwise_max(w, kZero);
      acc[c] = __builtin_elementwise_fma(w, (v2f){vj, vj}, acc[c]);
    }
  }
#pragma unroll
  for (int c = 0; c < FB_NCH; ++c) {
    atomicAdd(&vdst[i0 + (2 * c + 0) * FB_IBLK], acc[c].x * RESCALE);
    atomicAdd(&vdst[i0 + (2 * c + 1) * FB_IBLK], acc[c].y * RESCALE);
  }
}

__global__ __launch_bounds__(256) void fb_finalize_kernel(
    const float* __restrict__ v, float* __restrict__ out) {
  const int tid = threadIdx.x;
  float ss = 0.0f;
  for (int k = tid; k < NPTS; k += 256) { float x = v[k]; ss = fmaf(x, x, ss); }
  for (int off = 32; off > 0; off >>= 1) ss += __shfl_down(ss, off, 64);
  __shared__ float wsum[4];
  if ((tid & 63) == 0) wsum[tid >> 6] = ss;
  __syncthreads();
  float inv = 1.0f / (sqrtf(wsum[0] + wsum[1] + wsum[2] + wsum[3]) + 1e-6f);
  int i = blockIdx.x * 256 + tid;
  out[i] = v[i] * inv;
}

extern "C" void kernel_launch(void* const* d_in, const int* in_sizes, int n_in,
                              void* d_out, int out_size, void* d_ws, size_t ws_size,
                              hipStream_t stream) {
  const float* p2 = (const float*)d_in[0];   // 6144 x 2, float32
  const float* p3 = (const float*)d_in[1];   // 6144 x 3, float32
  float* out = (float*)d_out;                // 6144, float32

  float* w = (float*)d_ws;
  float4* rec = (float4*)w;                  // 6144 float4
  float*  z3a = w + 24576;                   // 6144 (8B-aligned base)
  float*  vA  = w + 32768;
  float*  vB  = w + 40960;
  float*  b2  = w + 49152;                   // fallback third buffer
  int*    arrive = (int*)(w + 57344);        // GRIDSZ epoch flags (poison-safe)
  int*    go     = (int*)(w + 61440);        // separate region

  void* args[] = { (void*)&p2, (void*)&p3, (void*)&rec, (void*)&z3a,
                   (void*)&vA, (void*)&vB, (void*)&arrive, (void*)&go, (void*)&out };
  hipError_t err = hipLaunchCooperativeKernel((const void*)power_kernel,
                                              dim3(GRIDSZ), dim3(IBLK),
                                              args, 0, stream);
  if (err != hipSuccess) {
    // Deterministic fallback: proven multi-launch path (R7, ~200 us).
    (void)hipGetLastError();   // clear sticky error
    fb_prep_kernel<<<NPTS / FB_IBLK, FB_IBLK, 0, stream>>>(p2, p3, rec, z3a, vA, vB);
    float* buf[3] = { vA, vB, b2 };
    for (int k = 0; k < 10; ++k) {
      fb_matvec_kernel<<<FB_NIBLK * FB_JPART, FB_IBLK, 0, stream>>>(
          rec, z3a, buf[k % 3], buf[(k + 1) % 3], buf[(k + 2) % 3]);
    }
    fb_finalize_kernel<<<NPTS / 256, 256, 0, stream>>>(buf[1], out);
  }
}